// Round 10
// baseline (1042.178 us; speedup 1.0000x reference)
//
#include <hip/hip_runtime.h>

// Elman RNN, B=256,T=256,I=128,H=512,O=1.
// v11: (a) v7's proven register split (KC_REG=3 pinned, rolling 3-buf stream)
//      on v10's proven 160KB LDS layout (KC_LDS=4, RS=512 XOR-swizzled)
//      -> streamed W 288KB/step (was 320).
//      (b) xproj fused into the main kernel as blocks 16..527, running on the
//      240 idle CUs concurrently with the 16 rnn blocks; per-(4t,bg) ready
//      flags (release/acquire, device scope). Kills the ~110us serial gap.
// rnn role: 16 blocks x 512 thr (8 waves, 1 block/CU), wave owns 64 h-cols.

#define B_   256
#define T_   256
#define I_   128
#define H_   512

typedef __attribute__((ext_vector_type(8))) short short8;
typedef __attribute__((ext_vector_type(4))) float f32x4;

static __device__ inline unsigned short f2bf(float f) {
    union { float f; unsigned u; } v; v.f = f;
    unsigned r = v.u + 0x7fffu + ((v.u >> 16) & 1u);   // RNE
    return (unsigned short)(r >> 16);
}
static __device__ inline float bf2f(unsigned short s) {
    union { unsigned u; float f; } v; v.u = ((unsigned)s) << 16;
    return v.f;
}
// tanh(x) = 1 - 2/(e^{2x}+1); raw v_rcp (~1 ulp f32) instead of IEEE div.
static __device__ inline float fast_tanh(float x) {
    float e = __expf(2.0f * x);
    float r = __builtin_amdgcn_rcpf(e + 1.0f);
    return __builtin_fmaf(-2.0f, r, 1.0f);
}
static __device__ inline short8 pack8(float4 lo, float4 hi) {
    short8 v;
    v[0] = (short)f2bf(lo.x); v[1] = (short)f2bf(lo.y);
    v[2] = (short)f2bf(lo.z); v[3] = (short)f2bf(lo.w);
    v[4] = (short)f2bf(hi.x); v[5] = (short)f2bf(hi.y);
    v[6] = (short)f2bf(hi.z); v[7] = (short)f2bf(hi.w);
    return v;
}

// ---------------------------------------------------------------------------
// FAST PATH
// ---------------------------------------------------------------------------
#define NKC   16   // K chunks of 32 covering W_hh (512)
#define RS3  512   // LDS h-row stride (bf16 elems), XOR-swizzled
#define KC_LDS 4   // kc 0..3   in LDS (128 KB)
#define KC_REG 3   // kc 4..6   pinned in VGPRs (48 regs) — v7's honest fit
#define KC_STR 9   // kc 7..15  streamed from L2, 3-buf rolling

#define NXB  512   // xproj sub-blocks (each = two (4t,bg) tiles)

// pack: Bpack (W_hh B-fragments), wia (W_ih A-fragments), bv, flags=0.
// grid 128 x 256 = 32768 threads exactly.
__global__ void pack_all(const float* __restrict__ W_hh,
                         const float* __restrict__ W_ih,
                         const float* __restrict__ b_ih,
                         const float* __restrict__ b_hh,
                         unsigned short* __restrict__ Bpack,
                         unsigned short* __restrict__ wia,
                         float* __restrict__ bv,
                         int* __restrict__ flags) {
    int idx = blockIdx.x * blockDim.x + threadIdx.x;
    {
        int lane = idx & 63;
        int kc   = (idx >> 6) % NKC;
        int nt   = (idx >> 6) / NKC;
        int n  = nt * 16 + (lane & 15);
        int k0 = kc * 32 + (lane >> 4) * 8;
        unsigned short* dst = Bpack + (size_t)idx * 8;
#pragma unroll
        for (int e = 0; e < 8; ++e)
            dst[e] = f2bf(W_hh[n * H_ + k0 + e]);
    }
    if (idx < 32 * 4 * 64) {
        int lane = idx & 63;
        int kc   = (idx >> 6) & 3;
        int nt   = idx >> 8;
        int row  = nt * 16 + (lane & 15);
        int k0   = kc * 32 + (lane >> 4) * 8;
        unsigned short* dst = wia + (size_t)idx * 8;
#pragma unroll
        for (int e = 0; e < 8; ++e)
            dst[e] = f2bf(W_ih[row * I_ + k0 + e]);
    }
    if (idx < H_) bv[idx] = b_ih[idx] + b_hh[idx];
    if (idx < 16 * 64) flags[idx] = 0;
}

// Fused kernel. Blocks 0..15: rnn (one per 16-row batch group).
// Blocks 16..527: xproj producers; block xb handles obid = xb*2 + (wave>=4),
//   obid = tg*16 + bg  (tg = 4-t group, bg = batch group), flag[obid] on done.
__global__ __launch_bounds__(512)
void rnn_fused(const unsigned short* __restrict__ Bpack,
               const unsigned short* __restrict__ wia,
               const float* __restrict__ bv,
               const float* __restrict__ x,
               unsigned short* __restrict__ xp,
               const float* __restrict__ fc_w,
               const float* __restrict__ fc_b,
               float* __restrict__ out,
               int* __restrict__ flags) {
    __shared__ __align__(16) unsigned short a_lds[2][16 * RS3];             // 32 KB
    __shared__ __align__(16) unsigned short w_lds[32 * KC_LDS * 64 * 8];    // 128 KB

    const int tid  = threadIdx.x;
    const int lane = tid & 63;
    const int w    = tid >> 6;
    const int q    = lane >> 4;
    const int mr   = lane & 15;

    if (blockIdx.x >= 16) {
        // ---------------- xproj producer role ----------------
        const int xb   = blockIdx.x - 16;
        const int obid = xb * 2 + (w >> 2);     // (tg,bg) tile id
        const int wl   = w & 3;                 // wave within tile
        const int t0   = (obid >> 4) * 4;
        const int bg   = obid & 15;

        // B fragments from x for 4 t's: col b-local = mr, k = kc*32+q*8+e
        short8 bf[4][4];
        const float* xbp = x + (size_t)(16 * bg + mr) * T_ * I_ + q * 8;
#pragma unroll
        for (int tt = 0; tt < 4; ++tt)
#pragma unroll
            for (int kc = 0; kc < 4; ++kc) {
                const float* p = xbp + (size_t)(t0 + tt) * I_ + kc * 32;
                bf[tt][kc] = pack8(*(const float4*)(p), *(const float4*)(p + 4));
            }

#pragma unroll
        for (int mt = 0; mt < 8; ++mt) {
            const int nt = wl * 8 + mt;
            f32x4 a[4];
#pragma unroll
            for (int tt = 0; tt < 4; ++tt) a[tt] = (f32x4)(0.0f);
#pragma unroll
            for (int kc = 0; kc < 4; ++kc) {
                short8 af = *(const short8*)&wia[((size_t)(nt * 4 + kc) * 64 + lane) * 8];
#pragma unroll
                for (int tt = 0; tt < 4; ++tt)
                    a[tt] = __builtin_amdgcn_mfma_f32_16x16x32_bf16(af, bf[tt][kc], a[tt], 0, 0, 0);
            }
#pragma unroll
            for (int tt = 0; tt < 4; ++tt) {
                unsigned short* dst = xp + ((size_t)((t0 + tt) * 16 + bg) * 512) * 16;
#pragma unroll
                for (int e = 0; e < 4; ++e) {
                    int n = nt * 16 + q * 4 + e;
                    dst[(size_t)n * 16 + mr] = f2bf(a[tt][e] + bv[n]);
                }
            }
        }

        __syncthreads();     // both halves' stores done
        __threadfence();     // device-scope release of xp stores
        if (tid == 0) {
            __hip_atomic_store(&flags[xb * 2],     1, __ATOMIC_RELEASE, __HIP_MEMORY_SCOPE_AGENT);
            __hip_atomic_store(&flags[xb * 2 + 1], 1, __ATOMIC_RELEASE, __HIP_MEMORY_SCOPE_AGENT);
        }
        return;
    }

    // ---------------- rnn role ----------------
    const int blk = blockIdx.x;
    const int bb  = blk * 16;

    // h0 = 0
    for (int i = tid; i < 16 * RS3; i += 512) a_lds[0][i] = 0;

    // preload LDS-resident W chunks (kc 0..3), fragment layout
    for (int i = tid; i < 32 * KC_LDS * 64; i += 512) {
        int l  = i & 63;
        int kc = (i >> 6) % KC_LDS;
        int nt = (i >> 6) / KC_LDS;
        *(short8*)&w_lds[(size_t)i * 8] =
            *(const short8*)(Bpack + ((size_t)(nt * NKC + kc) * 64 + l) * 8);
    }

    // W_hh kc 4..6, pinned register-resident (48 VGPRs)
    short8 wreg[KC_REG][4];
#pragma unroll
    for (int r = 0; r < KC_REG; ++r)
#pragma unroll
        for (int j = 0; j < 4; ++j)
            wreg[r][j] = *(const short8*)(Bpack +
                ((size_t)((4 * w + j) * NKC + KC_LDS + r) * 64 + lane) * 8);
#pragma unroll
    for (int r = 0; r < KC_REG; ++r)
#pragma unroll
        for (int j = 0; j < 4; ++j)
            asm volatile("" : "+v"(wreg[r][j]));

    __syncthreads();  // a_lds[0] zeros + w_lds visible

    f32x4 acc[4];
    short8 sb[3][4];   // streamed prefetch buffers (3 kc in flight)

    const int akey = (mr & 7) << 3;     // A-read swizzle key (row = mr)

    const unsigned short* xpt = xp + ((size_t)blk * 512) * 16;
    const size_t xstride = (size_t)16 * 512 * 16;   // per-t elems

    for (int t = 0; t < T_; ++t) {
        // wait for this 4-t group's xp tile (producers run on other CUs)
        if ((t & 3) == 0) {
            if (tid == 0) {
                const int fi = (t >> 2) * 16 + blk;
                int spins = 0;
                while (__hip_atomic_load(&flags[fi], __ATOMIC_ACQUIRE,
                                         __HIP_MEMORY_SCOPE_AGENT) == 0) {
                    if (++spins > (1 << 24)) break;   // fail-visible, never hang
                }
            }
            __syncthreads();
        }

        const unsigned short* A = a_lds[t & 1];
        unsigned short* An      = a_lds[(t & 1) ^ 1];

        // streamed W issue: kc 7,8,9 into sb[0..2]
#pragma unroll
        for (int s = 0; s < 3; ++s)
#pragma unroll
            for (int j = 0; j < 4; ++j)
                sb[s][j] = *(const short8*)(Bpack +
                    ((size_t)((4 * w + j) * NKC + KC_LDS + KC_REG + s) * 64 + lane) * 8);

        // xp prefetch (dense: contiguous 512B per wave per j), epilogue use
        ushort4 xpr[4];
#pragma unroll
        for (int j = 0; j < 4; ++j) {
            int col = (4 * w + j) * 16 + mr;
            xpr[j] = *(const ushort4*)(xpt + (size_t)col * 16 + q * 4);
        }

#pragma unroll
        for (int j = 0; j < 4; ++j) acc[j] = (f32x4)(0.0f);

        // --- LDS-resident kcs (0..3) ---
#pragma unroll
        for (int kc = 0; kc < KC_LDS; ++kc) {
            short8 af = *(const short8*)&A[mr * RS3 + ((kc * 32 + q * 8) ^ akey)];
#pragma unroll
            for (int j = 0; j < 4; ++j) {
                short8 bfr = *(const short8*)&w_lds[
                    (size_t)(((4 * w + j) * KC_LDS + kc) * 64 + lane) * 8];
                acc[j] = __builtin_amdgcn_mfma_f32_16x16x32_bf16(af, bfr, acc[j], 0, 0, 0);
            }
        }
        // --- register-resident kcs (4..6) ---
#pragma unroll
        for (int r = 0; r < KC_REG; ++r) {
            short8 af = *(const short8*)&A[mr * RS3 +
                (((KC_LDS + r) * 32 + q * 8) ^ akey)];
#pragma unroll
            for (int j = 0; j < 4; ++j)
                acc[j] = __builtin_amdgcn_mfma_f32_16x16x32_bf16(af, wreg[r][j], acc[j], 0, 0, 0);
        }
        // --- streamed kcs (7..15), rolling 3-deep refill ---
#pragma unroll
        for (int s = 0; s < KC_STR; ++s) {
            int kc = KC_LDS + KC_REG + s;
            short8 af = *(const short8*)&A[mr * RS3 + ((kc * 32 + q * 8) ^ akey)];
#pragma unroll
            for (int j = 0; j < 4; ++j)
                acc[j] = __builtin_amdgcn_mfma_f32_16x16x32_bf16(af, sb[s % 3][j], acc[j], 0, 0, 0);
            if (s + 3 < KC_STR) {
#pragma unroll
                for (int j = 0; j < 4; ++j)
                    sb[s % 3][j] = *(const short8*)(Bpack +
                        ((size_t)((4 * w + j) * NKC + kc + 3) * 64 + lane) * 8);
            }
        }

        // epilogue: h_{t+1} = tanh(acc + xp); swizzled write
#pragma unroll
        for (int j = 0; j < 4; ++j) {
            int col = (4 * w + j) * 16 + mr;
            const unsigned short* xj = (const unsigned short*)&xpr[j];
#pragma unroll
            for (int e = 0; e < 4; ++e) {
                int row = q * 4 + e;
                float hv = fast_tanh(acc[j][e] + bf2f(xj[e]));
                An[row * RS3 + (col ^ ((row & 7) << 3))] = f2bf(hv);
            }
        }
        xpt += xstride;
        __syncthreads();   // h_{t+1} visible; fences A reads vs next overwrite
    }

    // out[b] = h_T[b] . fc_w + fc_b ; h_T in buf 0 (T even), swizzled read
    {
        const int row = tid >> 5;
        const int l32 = tid & 31;
        const int fkey = (row & 7) << 3;
        float s = 0.0f;
        for (int k = l32; k < H_; k += 32)
            s += bf2f(a_lds[0][row * RS3 + (k ^ fkey)]) * fc_w[k];
#pragma unroll
        for (int off = 16; off > 0; off >>= 1)
            s += __shfl_down(s, off, 32);
        if (l32 == 0) out[bb + row] = s + fc_b[0];
    }
}

// ---------------------------------------------------------------------------
// FALLBACK PATH — round-0 kernel verbatim (640 KB workspace, measured 1214 µs)
// ---------------------------------------------------------------------------
#define FB_NKC   20
#define FB_NKC_H 16
#define FB_RS   648
#define FB_KC_LDS 4
#define FB_KC_REG 5
#define FB_KC_STR 7

__global__ void pack_w20(const float* __restrict__ W_ih,
                         const float* __restrict__ W_hh,
                         unsigned short* __restrict__ Bpack) {
    int idx = blockIdx.x * blockDim.x + threadIdx.x;
    if (idx >= 32 * FB_NKC * 64) return;
    int lane = idx & 63;
    int kc   = (idx >> 6) % FB_NKC;
    int nt   = (idx >> 6) / FB_NKC;
    int n  = nt * 16 + (lane & 15);
    int k0 = kc * 32 + (lane >> 4) * 8;
    unsigned short* dst = Bpack + (size_t)idx * 8;
#pragma unroll
    for (int e = 0; e < 8; ++e) {
        int k = k0 + e;
        float v = (k < H_) ? W_hh[n * H_ + k] : W_ih[n * I_ + (k - H_)];
        dst[e] = f2bf(v);
    }
}

__global__ __launch_bounds__(512, 2)
void rnn_fb(const float* __restrict__ x,
            const unsigned short* __restrict__ Bpack,
            const float* __restrict__ b_ih,
            const float* __restrict__ b_hh,
            const float* __restrict__ fc_w,
            const float* __restrict__ fc_b,
            float* __restrict__ out) {
    __shared__ __align__(16) unsigned short a_lds[16 * FB_RS];
    __shared__ __align__(16) unsigned short w_lds[32 * FB_KC_LDS * 64 * 8];

    const int tid  = threadIdx.x;
    const int lane = tid & 63;
    const int w    = tid >> 6;
    const int q    = lane >> 4;
    const int mr   = lane & 15;
    const int bb   = blockIdx.x * 16;

    for (int i = tid; i < 16 * FB_RS; i += 512) a_lds[i] = 0;

    for (int i = tid; i < 32 * FB_KC_LDS * 64; i += 512) {
        int l  = i & 63;
        int kc = (i >> 6) & (FB_KC_LDS - 1);
        int nt = i >> 8;
        *(short8*)&w_lds[(size_t)i * 8] =
            *(const short8*)(Bpack + ((size_t)(nt * FB_NKC + kc) * 64 + l) * 8);
    }

    float bias[4];
#pragma unroll
    for (int j = 0; j < 4; ++j) {
        int col = (4 * w + j) * 16 + mr;
        bias[j] = b_ih[col] + b_hh[col];
    }

    short8 wih[4][4];
#pragma unroll
    for (int j = 0; j < 4; ++j)
#pragma unroll
        for (int kx = 0; kx < 4; ++kx)
            wih[j][kx] = *(const short8*)(Bpack +
                ((size_t)((4 * w + j) * FB_NKC + FB_NKC_H + kx) * 64 + lane) * 8);

    short8 wreg[FB_KC_REG][4];
#pragma unroll
    for (int r = 0; r < FB_KC_REG; ++r)
#pragma unroll
        for (int j = 0; j < 4; ++j)
            wreg[r][j] = *(const short8*)(Bpack +
                ((size_t)((4 * w + j) * FB_NKC + FB_KC_LDS + r) * 64 + lane) * 8);

    const int xrow = tid >> 5;
    const int xc   = (tid & 31) * 4;
    const float* xbase = x + (size_t)(bb + xrow) * T_ * I_ + xc;
    float4 xreg = *(const float4*)(xbase);

    __syncthreads();

    f32x4 acc[4];
    short8 sb[3][4];

    for (int t = 0; t < T_; ++t) {
#pragma unroll
        for (int s = 0; s < 3; ++s)
#pragma unroll
            for (int j = 0; j < 4; ++j)
                sb[s][j] = *(const short8*)(Bpack +
                    ((size_t)((4 * w + j) * FB_NKC + FB_KC_LDS + FB_KC_REG + s) * 64 + lane) * 8);

        {
            ushort4 xs;
            xs.x = f2bf(xreg.x); xs.y = f2bf(xreg.y);
            xs.z = f2bf(xreg.z); xs.w = f2bf(xreg.w);
            *(ushort4*)&a_lds[xrow * FB_RS + H_ + xc] = xs;
        }
        __syncthreads();

        if (t + 1 < T_)
            xreg = *(const float4*)(xbase + (size_t)(t + 1) * I_);

#pragma unroll
        for (int j = 0; j < 4; ++j) acc[j] = (f32x4)(0.0f);

#pragma unroll
        for (int kc = 0; kc < FB_KC_LDS; ++kc) {
            short8 af = *(const short8*)&a_lds[mr * FB_RS + kc * 32 + q * 8];
#pragma unroll
            for (int j = 0; j < 4; ++j) {
                short8 bfr = *(const short8*)&w_lds[
                    (size_t)(((4 * w + j) * FB_KC_LDS + kc) * 64 + lane) * 8];
                acc[j] = __builtin_amdgcn_mfma_f32_16x16x32_bf16(af, bfr, acc[j], 0, 0, 0);
            }
        }
#pragma unroll
        for (int r = 0; r < FB_KC_REG; ++r) {
            short8 af = *(const short8*)&a_lds[mr * FB_RS + (FB_KC_LDS + r) * 32 + q * 8];
#pragma unroll
            for (int j = 0; j < 4; ++j)
                acc[j] = __builtin_amdgcn_mfma_f32_16x16x32_bf16(af, wreg[r][j], acc[j], 0, 0, 0);
        }
#pragma unroll
        for (int kx = 0; kx < 4; ++kx) {
            short8 af = *(const short8*)&a_lds[mr * FB_RS + H_ + kx * 32 + q * 8];
#pragma unroll
            for (int j = 0; j < 4; ++j)
                acc[j] = __builtin_amdgcn_mfma_f32_16x16x32_bf16(af, wih[j][kx], acc[j], 0, 0, 0);
        }
#pragma unroll
        for (int s = 0; s < FB_KC_STR; ++s) {
            int kc = FB_KC_LDS + FB_KC_REG + s;
            short8 af = *(const short8*)&a_lds[mr * FB_RS + kc * 32 + q * 8];
#pragma unroll
            for (int j = 0; j < 4; ++j)
                acc[j] = __builtin_amdgcn_mfma_f32_16x16x32_bf16(af, sb[s % 3][j], acc[j], 0, 0, 0);
            if (s + 3 < FB_KC_STR) {
#pragma unroll
                for (int j = 0; j < 4; ++j)
                    sb[s % 3][j] = *(const short8*)(Bpack +
                        ((size_t)((4 * w + j) * FB_NKC + kc + 3) * 64 + lane) * 8);
            }
        }
        __syncthreads();

#pragma unroll
        for (int j = 0; j < 4; ++j) {
            int col = (4 * w + j) * 16 + mr;
#pragma unroll
            for (int e = 0; e < 4; ++e) {
                float hv = fast_tanh(acc[j][e] + bias[j]);
                a_lds[(q * 4 + e) * FB_RS + col] = f2bf(hv);
            }
        }
    }
    __syncthreads();

    {
        const int row = tid >> 5;
        const int l32 = tid & 31;
        float s = 0.0f;
        for (int k = l32; k < H_; k += 32)
            s += bf2f(a_lds[row * FB_RS + k]) * fc_w[k];
#pragma unroll
        for (int off = 16; off > 0; off >>= 1)
            s += __shfl_down(s, off, 32);
        if (l32 == 0) out[bb + row] = s + fc_b[0];
    }
}

// ---------------------------------------------------------------------------

extern "C" void kernel_launch(void* const* d_in, const int* in_sizes, int n_in,
                              void* d_out, int out_size, void* d_ws, size_t ws_size,
                              hipStream_t stream) {
    const float* x    = (const float*)d_in[0];
    const float* W_ih = (const float*)d_in[1];
    const float* W_hh = (const float*)d_in[2];
    const float* b_ih = (const float*)d_in[3];
    const float* b_hh = (const float*)d_in[4];
    const float* fc_w = (const float*)d_in[5];
    const float* fc_b = (const float*)d_in[6];

    const size_t BP_SZ  = (size_t)32 * NKC * 64 * 8 * 2;   // 512 KB
    const size_t WIA_SZ = (size_t)32 * 4 * 64 * 8 * 2;     // 128 KB
    const size_t BV_SZ  = (size_t)H_ * 4;                  // 2 KB
    const size_t FL_SZ  = (size_t)16 * 64 * 4;             // 4 KB
    const size_t XP_OFF = BP_SZ + WIA_SZ + BV_SZ + FL_SZ;
    const size_t NEED_FAST = XP_OFF + (size_t)T_ * H_ * B_ * 2;   // +64 MB

    if (ws_size >= NEED_FAST) {
        unsigned short* Bpack = (unsigned short*)d_ws;
        unsigned short* wia   = (unsigned short*)((char*)d_ws + BP_SZ);
        float*          bv    = (float*)((char*)d_ws + BP_SZ + WIA_SZ);
        int*            flags = (int*)((char*)d_ws + BP_SZ + WIA_SZ + BV_SZ);
        unsigned short* xp    = (unsigned short*)((char*)d_ws + XP_OFF);
        pack_all<<<128, 256, 0, stream>>>(W_hh, W_ih, b_ih, b_hh,
                                          Bpack, wia, bv, flags);
        rnn_fused<<<16 + NXB, 512, 0, stream>>>(Bpack, wia, bv, x, xp,
                                                fc_w, fc_b, (float*)d_out, flags);
    } else {
        unsigned short* Bpack = (unsigned short*)d_ws;                 // 640 KB
        pack_w20<<<160, 256, 0, stream>>>(W_ih, W_hh, Bpack);
        rnn_fb<<<16, 512, 0, stream>>>(x, Bpack, b_ih, b_hh, fc_w, fc_b, (float*)d_out);
    }
}

// Round 11
// 968.331 us; speedup vs baseline: 1.0763x; 1.0763x over previous
//
#include <hip/hip_runtime.h>

// Elman RNN, B=256,T=256,I=128,H=512,O=1.
// v12 consolidation: v11's fusion poisoned L2 (agent-scope acquire invalidates
//      the XCD L2 every 4 steps -> streamed W refetched from L3; FETCH 35->52MB,
//      rnn step 2.0->3.9us). Revert to separate kernels; keep only proven parts:
//      - rnn: KC_LDS=4 (v10 160KB LDS layout, XOR swizzle) + v7 register split
//        (KC_REG=3 pinned / KC_STR=9 rolling) -> streamed 288KB/step (v7: 320).
//      - xproj: v10 prepacked-wia pipeline (110us gap, best measured).
// rnn: 16 blocks x 512 thr (8 waves, 1 block/CU), wave owns 64 h-cols.

#define B_   256
#define T_   256
#define I_   128
#define H_   512

typedef __attribute__((ext_vector_type(8))) short short8;
typedef __attribute__((ext_vector_type(4))) float f32x4;

static __device__ inline unsigned short f2bf(float f) {
    union { float f; unsigned u; } v; v.f = f;
    unsigned r = v.u + 0x7fffu + ((v.u >> 16) & 1u);   // RNE
    return (unsigned short)(r >> 16);
}
static __device__ inline float bf2f(unsigned short s) {
    union { unsigned u; float f; } v; v.u = ((unsigned)s) << 16;
    return v.f;
}
// tanh(x) = 1 - 2/(e^{2x}+1); raw v_rcp (~1 ulp f32) instead of IEEE div.
static __device__ inline float fast_tanh(float x) {
    float e = __expf(2.0f * x);
    float r = __builtin_amdgcn_rcpf(e + 1.0f);
    return __builtin_fmaf(-2.0f, r, 1.0f);
}
static __device__ inline short8 pack8(float4 lo, float4 hi) {
    short8 v;
    v[0] = (short)f2bf(lo.x); v[1] = (short)f2bf(lo.y);
    v[2] = (short)f2bf(lo.z); v[3] = (short)f2bf(lo.w);
    v[4] = (short)f2bf(hi.x); v[5] = (short)f2bf(hi.y);
    v[6] = (short)f2bf(hi.z); v[7] = (short)f2bf(hi.w);
    return v;
}

// ---------------------------------------------------------------------------
// FAST PATH
// ---------------------------------------------------------------------------
#define NKC   16   // K chunks of 32 covering W_hh (512)
#define RS3  512   // LDS h-row stride (bf16 elems), XOR-swizzled
#define KC_LDS 4   // kc 0..3   in LDS (128 KB)
#define KC_REG 3   // kc 4..6   pinned in VGPRs (48 regs)
#define KC_STR 9   // kc 7..15  streamed from L2, 3-buf rolling

// pack: Bpack (W_hh B-fragments), wia (W_ih A-fragments), bv.
// grid 128 x 256 = 32768 threads exactly.
__global__ void pack_all(const float* __restrict__ W_hh,
                         const float* __restrict__ W_ih,
                         const float* __restrict__ b_ih,
                         const float* __restrict__ b_hh,
                         unsigned short* __restrict__ Bpack,
                         unsigned short* __restrict__ wia,
                         float* __restrict__ bv) {
    int idx = blockIdx.x * blockDim.x + threadIdx.x;
    {
        int lane = idx & 63;
        int kc   = (idx >> 6) % NKC;
        int nt   = (idx >> 6) / NKC;
        int n  = nt * 16 + (lane & 15);
        int k0 = kc * 32 + (lane >> 4) * 8;
        unsigned short* dst = Bpack + (size_t)idx * 8;
#pragma unroll
        for (int e = 0; e < 8; ++e)
            dst[e] = f2bf(W_hh[n * H_ + k0 + e]);
    }
    if (idx < 32 * 4 * 64) {
        int lane = idx & 63;
        int kc   = (idx >> 6) & 3;
        int nt   = idx >> 8;
        int row  = nt * 16 + (lane & 15);
        int k0   = kc * 32 + (lane >> 4) * 8;
        unsigned short* dst = wia + (size_t)idx * 8;
#pragma unroll
        for (int e = 0; e < 8; ++e)
            dst[e] = f2bf(W_ih[row * I_ + k0 + e]);
    }
    if (idx < H_) bv[idx] = b_ih[idx] + b_hh[idx];
}

// xp[((t*16+bg)*512 + n)*16 + bl] = bf16( W_ih[n]·x[16bg+bl][t] + bv[n] )
// grid (T_/4, 16), block 256 (4 waves), 4 consecutive t per block.
__global__ __launch_bounds__(256)
void xproj_k(const float* __restrict__ x,
             const unsigned short* __restrict__ wia,
             const float* __restrict__ bv,
             unsigned short* __restrict__ xp) {
    const int tid  = threadIdx.x;
    const int lane = tid & 63;
    const int w    = tid >> 6;      // 0..3
    const int mr   = lane & 15;
    const int q    = lane >> 4;
    const int t0   = blockIdx.x * 4;
    const int bg   = blockIdx.y;    // 0..15

    // B fragments from x for 4 t's: col b-local = mr, k = i = kc*32 + q*8 + e
    short8 bf[4][4];
    const float* xb = x + (size_t)(16 * bg + mr) * T_ * I_ + q * 8;
#pragma unroll
    for (int tt = 0; tt < 4; ++tt)
#pragma unroll
        for (int kc = 0; kc < 4; ++kc) {
            const float* p = xb + (size_t)(t0 + tt) * I_ + kc * 32;
            bf[tt][kc] = pack8(*(const float4*)(p), *(const float4*)(p + 4));
        }

#pragma unroll
    for (int mt = 0; mt < 8; ++mt) {
        const int nt = w * 8 + mt;                   // n-tile this wave/mt
        f32x4 a[4];
#pragma unroll
        for (int tt = 0; tt < 4; ++tt) a[tt] = (f32x4)(0.0f);
#pragma unroll
        for (int kc = 0; kc < 4; ++kc) {
            short8 af = *(const short8*)&wia[((size_t)(nt * 4 + kc) * 64 + lane) * 8];
#pragma unroll
            for (int tt = 0; tt < 4; ++tt)
                a[tt] = __builtin_amdgcn_mfma_f32_16x16x32_bf16(af, bf[tt][kc], a[tt], 0, 0, 0);
        }
        // D: row n-local = q*4+e, col b-local = mr
#pragma unroll
        for (int tt = 0; tt < 4; ++tt) {
            unsigned short* dst = xp + ((size_t)((t0 + tt) * 16 + bg) * 512) * 16;
#pragma unroll
            for (int e = 0; e < 4; ++e) {
                int n = nt * 16 + q * 4 + e;
                dst[(size_t)n * 16 + mr] = f2bf(a[tt][e] + bv[n]);
            }
        }
    }
}

__global__ __launch_bounds__(512)
void rnn_fast(const unsigned short* __restrict__ Bpack,
              const unsigned short* __restrict__ xp,
              const float* __restrict__ fc_w,
              const float* __restrict__ fc_b,
              float* __restrict__ out) {
    __shared__ __align__(16) unsigned short a_lds[2][16 * RS3];             // 32 KB
    __shared__ __align__(16) unsigned short w_lds[32 * KC_LDS * 64 * 8];    // 128 KB

    const int tid  = threadIdx.x;
    const int lane = tid & 63;
    const int w    = tid >> 6;      // wave 0..7, owns cols [64w, 64w+64)
    const int q    = lane >> 4;     // 0..3
    const int mr   = lane & 15;
    const int blk  = blockIdx.x;    // batch group
    const int bb   = blk * 16;

    // h0 = 0
    for (int i = tid; i < 16 * RS3; i += 512) a_lds[0][i] = 0;

    // preload LDS-resident W chunks (kc 0..3), fragment layout
    for (int i = tid; i < 32 * KC_LDS * 64; i += 512) {
        int l  = i & 63;
        int kc = (i >> 6) % KC_LDS;
        int nt = (i >> 6) / KC_LDS;
        *(short8*)&w_lds[(size_t)i * 8] =
            *(const short8*)(Bpack + ((size_t)(nt * NKC + kc) * 64 + l) * 8);
    }

    // W_hh kc 4..6, pinned register-resident (48 VGPRs) — the honest fit
    short8 wreg[KC_REG][4];
#pragma unroll
    for (int r = 0; r < KC_REG; ++r)
#pragma unroll
        for (int j = 0; j < 4; ++j)
            wreg[r][j] = *(const short8*)(Bpack +
                ((size_t)((4 * w + j) * NKC + KC_LDS + r) * 64 + lane) * 8);
#pragma unroll
    for (int r = 0; r < KC_REG; ++r)
#pragma unroll
        for (int j = 0; j < 4; ++j)
            asm volatile("" : "+v"(wreg[r][j]));

    __syncthreads();  // a_lds[0] zeros + w_lds visible

    f32x4 acc[4];
    short8 sb[3][4];   // streamed prefetch buffers (3 kc in flight)

    const int akey = (mr & 7) << 3;     // A-read swizzle key (row = mr)

    const unsigned short* xpt = xp + ((size_t)blk * 512) * 16;
    const size_t xstride = (size_t)16 * 512 * 16;   // per-t elems

    for (int t = 0; t < T_; ++t) {
        const unsigned short* A = a_lds[t & 1];
        unsigned short* An      = a_lds[(t & 1) ^ 1];

        // streamed W issue: kc 7,8,9 into sb[0..2]
#pragma unroll
        for (int s = 0; s < 3; ++s)
#pragma unroll
            for (int j = 0; j < 4; ++j)
                sb[s][j] = *(const short8*)(Bpack +
                    ((size_t)((4 * w + j) * NKC + KC_LDS + KC_REG + s) * 64 + lane) * 8);

        // xp prefetch (dense: contiguous 512B per wave per j), epilogue use
        ushort4 xpr[4];
#pragma unroll
        for (int j = 0; j < 4; ++j) {
            int col = (4 * w + j) * 16 + mr;
            xpr[j] = *(const ushort4*)(xpt + (size_t)col * 16 + q * 4);
        }

#pragma unroll
        for (int j = 0; j < 4; ++j) acc[j] = (f32x4)(0.0f);

        // --- LDS-resident kcs (0..3) ---
#pragma unroll
        for (int kc = 0; kc < KC_LDS; ++kc) {
            short8 af = *(const short8*)&A[mr * RS3 + ((kc * 32 + q * 8) ^ akey)];
#pragma unroll
            for (int j = 0; j < 4; ++j) {
                short8 bfr = *(const short8*)&w_lds[
                    (size_t)(((4 * w + j) * KC_LDS + kc) * 64 + lane) * 8];
                acc[j] = __builtin_amdgcn_mfma_f32_16x16x32_bf16(af, bfr, acc[j], 0, 0, 0);
            }
        }
        // --- register-resident kcs (4..6) ---
#pragma unroll
        for (int r = 0; r < KC_REG; ++r) {
            short8 af = *(const short8*)&A[mr * RS3 +
                (((KC_LDS + r) * 32 + q * 8) ^ akey)];
#pragma unroll
            for (int j = 0; j < 4; ++j)
                acc[j] = __builtin_amdgcn_mfma_f32_16x16x32_bf16(af, wreg[r][j], acc[j], 0, 0, 0);
        }
        // --- streamed kcs (7..15), rolling 3-deep refill ---
#pragma unroll
        for (int s = 0; s < KC_STR; ++s) {
            int kc = KC_LDS + KC_REG + s;
            short8 af = *(const short8*)&A[mr * RS3 + ((kc * 32 + q * 8) ^ akey)];
#pragma unroll
            for (int j = 0; j < 4; ++j)
                acc[j] = __builtin_amdgcn_mfma_f32_16x16x32_bf16(af, sb[s % 3][j], acc[j], 0, 0, 0);
            if (s + 3 < KC_STR) {
#pragma unroll
                for (int j = 0; j < 4; ++j)
                    sb[s % 3][j] = *(const short8*)(Bpack +
                        ((size_t)((4 * w + j) * NKC + kc + 3) * 64 + lane) * 8);
            }
        }

        // epilogue: h_{t+1} = tanh(acc + xp); swizzled write
#pragma unroll
        for (int j = 0; j < 4; ++j) {
            int col = (4 * w + j) * 16 + mr;
            const unsigned short* xj = (const unsigned short*)&xpr[j];
#pragma unroll
            for (int e = 0; e < 4; ++e) {
                int row = q * 4 + e;
                float hv = fast_tanh(acc[j][e] + bf2f(xj[e]));
                An[row * RS3 + (col ^ ((row & 7) << 3))] = f2bf(hv);
            }
        }
        xpt += xstride;
        __syncthreads();   // h_{t+1} visible; fences A reads vs next overwrite
    }

    // out[b] = h_T[b] . fc_w + fc_b ; h_T in buf 0 (T even), swizzled read
    {
        const int row = tid >> 5;
        const int l32 = tid & 31;
        const int fkey = (row & 7) << 3;
        float s = 0.0f;
        for (int k = l32; k < H_; k += 32)
            s += bf2f(a_lds[0][row * RS3 + (k ^ fkey)]) * fc_w[k];
#pragma unroll
        for (int off = 16; off > 0; off >>= 1)
            s += __shfl_down(s, off, 32);
        if (l32 == 0) out[bb + row] = s + fc_b[0];
    }
}

// ---------------------------------------------------------------------------
// FALLBACK PATH — round-0 kernel verbatim (640 KB workspace, measured 1214 µs)
// ---------------------------------------------------------------------------
#define FB_NKC   20
#define FB_NKC_H 16
#define FB_RS   648
#define FB_KC_LDS 4
#define FB_KC_REG 5
#define FB_KC_STR 7

__global__ void pack_w20(const float* __restrict__ W_ih,
                         const float* __restrict__ W_hh,
                         unsigned short* __restrict__ Bpack) {
    int idx = blockIdx.x * blockDim.x + threadIdx.x;
    if (idx >= 32 * FB_NKC * 64) return;
    int lane = idx & 63;
    int kc   = (idx >> 6) % FB_NKC;
    int nt   = (idx >> 6) / FB_NKC;
    int n  = nt * 16 + (lane & 15);
    int k0 = kc * 32 + (lane >> 4) * 8;
    unsigned short* dst = Bpack + (size_t)idx * 8;
#pragma unroll
    for (int e = 0; e < 8; ++e) {
        int k = k0 + e;
        float v = (k < H_) ? W_hh[n * H_ + k] : W_ih[n * I_ + (k - H_)];
        dst[e] = f2bf(v);
    }
}

__global__ __launch_bounds__(512, 2)
void rnn_fb(const float* __restrict__ x,
            const unsigned short* __restrict__ Bpack,
            const float* __restrict__ b_ih,
            const float* __restrict__ b_hh,
            const float* __restrict__ fc_w,
            const float* __restrict__ fc_b,
            float* __restrict__ out) {
    __shared__ __align__(16) unsigned short a_lds[16 * FB_RS];
    __shared__ __align__(16) unsigned short w_lds[32 * FB_KC_LDS * 64 * 8];

    const int tid  = threadIdx.x;
    const int lane = tid & 63;
    const int w    = tid >> 6;
    const int q    = lane >> 4;
    const int mr   = lane & 15;
    const int bb   = blockIdx.x * 16;

    for (int i = tid; i < 16 * FB_RS; i += 512) a_lds[i] = 0;

    for (int i = tid; i < 32 * FB_KC_LDS * 64; i += 512) {
        int l  = i & 63;
        int kc = (i >> 6) & (FB_KC_LDS - 1);
        int nt = i >> 8;
        *(short8*)&w_lds[(size_t)i * 8] =
            *(const short8*)(Bpack + ((size_t)(nt * FB_NKC + kc) * 64 + l) * 8);
    }

    float bias[4];
#pragma unroll
    for (int j = 0; j < 4; ++j) {
        int col = (4 * w + j) * 16 + mr;
        bias[j] = b_ih[col] + b_hh[col];
    }

    short8 wih[4][4];
#pragma unroll
    for (int j = 0; j < 4; ++j)
#pragma unroll
        for (int kx = 0; kx < 4; ++kx)
            wih[j][kx] = *(const short8*)(Bpack +
                ((size_t)((4 * w + j) * FB_NKC + FB_NKC_H + kx) * 64 + lane) * 8);

    short8 wreg[FB_KC_REG][4];
#pragma unroll
    for (int r = 0; r < FB_KC_REG; ++r)
#pragma unroll
        for (int j = 0; j < 4; ++j)
            wreg[r][j] = *(const short8*)(Bpack +
                ((size_t)((4 * w + j) * FB_NKC + FB_KC_LDS + r) * 64 + lane) * 8);

    const int xrow = tid >> 5;
    const int xc   = (tid & 31) * 4;
    const float* xbase = x + (size_t)(bb + xrow) * T_ * I_ + xc;
    float4 xreg = *(const float4*)(xbase);

    __syncthreads();

    f32x4 acc[4];
    short8 sb[3][4];

    for (int t = 0; t < T_; ++t) {
#pragma unroll
        for (int s = 0; s < 3; ++s)
#pragma unroll
            for (int j = 0; j < 4; ++j)
                sb[s][j] = *(const short8*)(Bpack +
                    ((size_t)((4 * w + j) * FB_NKC + FB_KC_LDS + FB_KC_REG + s) * 64 + lane) * 8);

        {
            ushort4 xs;
            xs.x = f2bf(xreg.x); xs.y = f2bf(xreg.y);
            xs.z = f2bf(xreg.z); xs.w = f2bf(xreg.w);
            *(ushort4*)&a_lds[xrow * FB_RS + H_ + xc] = xs;
        }
        __syncthreads();

        if (t + 1 < T_)
            xreg = *(const float4*)(xbase + (size_t)(t + 1) * I_);

#pragma unroll
        for (int j = 0; j < 4; ++j) acc[j] = (f32x4)(0.0f);

#pragma unroll
        for (int kc = 0; kc < FB_KC_LDS; ++kc) {
            short8 af = *(const short8*)&a_lds[mr * FB_RS + kc * 32 + q * 8];
#pragma unroll
            for (int j = 0; j < 4; ++j) {
                short8 bfr = *(const short8*)&w_lds[
                    (size_t)(((4 * w + j) * FB_KC_LDS + kc) * 64 + lane) * 8];
                acc[j] = __builtin_amdgcn_mfma_f32_16x16x32_bf16(af, bfr, acc[j], 0, 0, 0);
            }
        }
#pragma unroll
        for (int r = 0; r < FB_KC_REG; ++r) {
            short8 af = *(const short8*)&a_lds[mr * FB_RS + (FB_KC_LDS + r) * 32 + q * 8];
#pragma unroll
            for (int j = 0; j < 4; ++j)
                acc[j] = __builtin_amdgcn_mfma_f32_16x16x32_bf16(af, wreg[r][j], acc[j], 0, 0, 0);
        }
#pragma unroll
        for (int kx = 0; kx < 4; ++kx) {
            short8 af = *(const short8*)&a_lds[mr * FB_RS + H_ + kx * 32 + q * 8];
#pragma unroll
            for (int j = 0; j < 4; ++j)
                acc[j] = __builtin_amdgcn_mfma_f32_16x16x32_bf16(af, wih[j][kx], acc[j], 0, 0, 0);
        }
#pragma unroll
        for (int s = 0; s < FB_KC_STR; ++s) {
            int kc = FB_KC_LDS + FB_KC_REG + s;
            short8 af = *(const short8*)&a_lds[mr * FB_RS + kc * 32 + q * 8];
#pragma unroll
            for (int j = 0; j < 4; ++j)
                acc[j] = __builtin_amdgcn_mfma_f32_16x16x32_bf16(af, sb[s % 3][j], acc[j], 0, 0, 0);
            if (s + 3 < FB_KC_STR) {
#pragma unroll
                for (int j = 0; j < 4; ++j)
                    sb[s % 3][j] = *(const short8*)(Bpack +
                        ((size_t)((4 * w + j) * FB_NKC + kc + 3) * 64 + lane) * 8);
            }
        }
        __syncthreads();

#pragma unroll
        for (int j = 0; j < 4; ++j) {
            int col = (4 * w + j) * 16 + mr;
#pragma unroll
            for (int e = 0; e < 4; ++e) {
                float hv = fast_tanh(acc[j][e] + bias[j]);
                a_lds[(q * 4 + e) * FB_RS + col] = f2bf(hv);
            }
        }
    }
    __syncthreads();

    {
        const int row = tid >> 5;
        const int l32 = tid & 31;
        float s = 0.0f;
        for (int k = l32; k < H_; k += 32)
            s += bf2f(a_lds[row * FB_RS + k]) * fc_w[k];
#pragma unroll
        for (int off = 16; off > 0; off >>= 1)
            s += __shfl_down(s, off, 32);
        if (l32 == 0) out[bb + row] = s + fc_b[0];
    }
}

// ---------------------------------------------------------------------------

extern "C" void kernel_launch(void* const* d_in, const int* in_sizes, int n_in,
                              void* d_out, int out_size, void* d_ws, size_t ws_size,
                              hipStream_t stream) {
    const float* x    = (const float*)d_in[0];
    const float* W_ih = (const float*)d_in[1];
    const float* W_hh = (const float*)d_in[2];
    const float* b_ih = (const float*)d_in[3];
    const float* b_hh = (const float*)d_in[4];
    const float* fc_w = (const float*)d_in[5];
    const float* fc_b = (const float*)d_in[6];

    const size_t BP_SZ  = (size_t)32 * NKC * 64 * 8 * 2;   // 512 KB
    const size_t WIA_SZ = (size_t)32 * 4 * 64 * 8 * 2;     // 128 KB
    const size_t BV_SZ  = (size_t)H_ * 4;                  // 2 KB
    const size_t XP_OFF = BP_SZ + WIA_SZ + BV_SZ;
    const size_t NEED_FAST = XP_OFF + (size_t)T_ * H_ * B_ * 2;   // +64 MB

    if (ws_size >= NEED_FAST) {
        unsigned short* Bpack = (unsigned short*)d_ws;
        unsigned short* wia   = (unsigned short*)((char*)d_ws + BP_SZ);
        float*          bv    = (float*)((char*)d_ws + BP_SZ + WIA_SZ);
        unsigned short* xp    = (unsigned short*)((char*)d_ws + XP_OFF);
        pack_all<<<128, 256, 0, stream>>>(W_hh, W_ih, b_ih, b_hh, Bpack, wia, bv);
        xproj_k<<<dim3(T_ / 4, 16), 256, 0, stream>>>(x, wia, bv, xp);
        rnn_fast<<<16, 512, 0, stream>>>(Bpack, xp, fc_w, fc_b, (float*)d_out);
    } else {
        unsigned short* Bpack = (unsigned short*)d_ws;                 // 640 KB
        pack_w20<<<160, 256, 0, stream>>>(W_ih, W_hh, Bpack);
        rnn_fb<<<16, 512, 0, stream>>>(x, Bpack, b_ih, b_hh, fc_w, fc_b, (float*)d_out);
    }
}

// Round 12
// 631.987 us; speedup vs baseline: 1.6491x; 1.5322x over previous
//
#include <hip/hip_runtime.h>

// Elman RNN, B=256,T=256,I=128,H=512,O=1.
// v13 consolidation. Evidence: v10/v12 proved the KC_LDS=4/160KB-LDS layout
//   itself costs +67% (862 vs 515 at equal MFMA/VALU cycles -> pure LDS stall).
//   So: rnn_fast reverted to v7 VERBATIM (KC_LDS=3, RS2=520 pad, KC_REG=3
//   pinned, KC_STR=10 rolling, rcp-tanh, dense xp) = 515.8us proven.
//   xproj kept from v12 (prepacked wia/bv + 4-t batching) = 106us gap proven.
// rnn: 16 blocks x 512 thr (8 waves, 1 block/CU), wave owns 64 h-cols.

#define B_   256
#define T_   256
#define I_   128
#define H_   512

typedef __attribute__((ext_vector_type(8))) short short8;
typedef __attribute__((ext_vector_type(4))) float f32x4;

static __device__ inline unsigned short f2bf(float f) {
    union { float f; unsigned u; } v; v.f = f;
    unsigned r = v.u + 0x7fffu + ((v.u >> 16) & 1u);   // RNE
    return (unsigned short)(r >> 16);
}
static __device__ inline float bf2f(unsigned short s) {
    union { unsigned u; float f; } v; v.u = ((unsigned)s) << 16;
    return v.f;
}
// tanh(x) = 1 - 2/(e^{2x}+1); raw v_rcp (~1 ulp f32) instead of IEEE div.
static __device__ inline float fast_tanh(float x) {
    float e = __expf(2.0f * x);
    float r = __builtin_amdgcn_rcpf(e + 1.0f);
    return __builtin_fmaf(-2.0f, r, 1.0f);
}
static __device__ inline short8 pack8(float4 lo, float4 hi) {
    short8 v;
    v[0] = (short)f2bf(lo.x); v[1] = (short)f2bf(lo.y);
    v[2] = (short)f2bf(lo.z); v[3] = (short)f2bf(lo.w);
    v[4] = (short)f2bf(hi.x); v[5] = (short)f2bf(hi.y);
    v[6] = (short)f2bf(hi.z); v[7] = (short)f2bf(hi.w);
    return v;
}

// ---------------------------------------------------------------------------
// FAST PATH
// ---------------------------------------------------------------------------
#define NKC   16   // K chunks of 32 covering W_hh (512)
#define RS2  520   // LDS h-row stride in bf16 elems (512 + 8 pad) — v7 layout
#define KC_LDS 3   // kc 0..2  in LDS (96 KB)
#define KC_REG 3   // kc 3..5  pinned in VGPRs (48 regs)
#define KC_STR 10  // kc 6..15 streamed from L2, 3-buf rolling

// pack: Bpack (W_hh B-fragments), wia (W_ih A-fragments), bv.
// grid 128 x 256 = 32768 threads exactly.
__global__ void pack_all(const float* __restrict__ W_hh,
                         const float* __restrict__ W_ih,
                         const float* __restrict__ b_ih,
                         const float* __restrict__ b_hh,
                         unsigned short* __restrict__ Bpack,
                         unsigned short* __restrict__ wia,
                         float* __restrict__ bv) {
    int idx = blockIdx.x * blockDim.x + threadIdx.x;
    {
        int lane = idx & 63;
        int kc   = (idx >> 6) % NKC;
        int nt   = (idx >> 6) / NKC;
        int n  = nt * 16 + (lane & 15);
        int k0 = kc * 32 + (lane >> 4) * 8;
        unsigned short* dst = Bpack + (size_t)idx * 8;
#pragma unroll
        for (int e = 0; e < 8; ++e)
            dst[e] = f2bf(W_hh[n * H_ + k0 + e]);
    }
    if (idx < 32 * 4 * 64) {
        int lane = idx & 63;
        int kc   = (idx >> 6) & 3;
        int nt   = idx >> 8;
        int row  = nt * 16 + (lane & 15);
        int k0   = kc * 32 + (lane >> 4) * 8;
        unsigned short* dst = wia + (size_t)idx * 8;
#pragma unroll
        for (int e = 0; e < 8; ++e)
            dst[e] = f2bf(W_ih[row * I_ + k0 + e]);
    }
    if (idx < H_) bv[idx] = b_ih[idx] + b_hh[idx];
}

// xp[((t*16+bg)*512 + n)*16 + bl] = bf16( W_ih[n]·x[16bg+bl][t] + bv[n] )
// grid (T_/4, 16), block 256 (4 waves), 4 consecutive t per block.
__global__ __launch_bounds__(256)
void xproj_k(const float* __restrict__ x,
             const unsigned short* __restrict__ wia,
             const float* __restrict__ bv,
             unsigned short* __restrict__ xp) {
    const int tid  = threadIdx.x;
    const int lane = tid & 63;
    const int w    = tid >> 6;      // 0..3
    const int mr   = lane & 15;
    const int q    = lane >> 4;
    const int t0   = blockIdx.x * 4;
    const int bg   = blockIdx.y;    // 0..15

    // B fragments from x for 4 t's: col b-local = mr, k = i = kc*32 + q*8 + e
    short8 bf[4][4];
    const float* xb = x + (size_t)(16 * bg + mr) * T_ * I_ + q * 8;
#pragma unroll
    for (int tt = 0; tt < 4; ++tt)
#pragma unroll
        for (int kc = 0; kc < 4; ++kc) {
            const float* p = xb + (size_t)(t0 + tt) * I_ + kc * 32;
            bf[tt][kc] = pack8(*(const float4*)(p), *(const float4*)(p + 4));
        }

#pragma unroll
    for (int mt = 0; mt < 8; ++mt) {
        const int nt = w * 8 + mt;                   // n-tile this wave/mt
        f32x4 a[4];
#pragma unroll
        for (int tt = 0; tt < 4; ++tt) a[tt] = (f32x4)(0.0f);
#pragma unroll
        for (int kc = 0; kc < 4; ++kc) {
            short8 af = *(const short8*)&wia[((size_t)(nt * 4 + kc) * 64 + lane) * 8];
#pragma unroll
            for (int tt = 0; tt < 4; ++tt)
                a[tt] = __builtin_amdgcn_mfma_f32_16x16x32_bf16(af, bf[tt][kc], a[tt], 0, 0, 0);
        }
        // D: row n-local = q*4+e, col b-local = mr
#pragma unroll
        for (int tt = 0; tt < 4; ++tt) {
            unsigned short* dst = xp + ((size_t)((t0 + tt) * 16 + bg) * 512) * 16;
#pragma unroll
            for (int e = 0; e < 4; ++e) {
                int n = nt * 16 + q * 4 + e;
                dst[(size_t)n * 16 + mr] = f2bf(a[tt][e] + bv[n]);
            }
        }
    }
}

// v7-verbatim main loop (measured 515.8 us, LDS 131584, VGPR 128).
__global__ __launch_bounds__(512)
void rnn_fast(const unsigned short* __restrict__ Bpack,
              const unsigned short* __restrict__ xp,
              const float* __restrict__ fc_w,
              const float* __restrict__ fc_b,
              float* __restrict__ out) {
    __shared__ __align__(16) unsigned short a_lds[2][16 * RS2];            // 33.3 KB
    __shared__ __align__(16) unsigned short w_lds[32 * KC_LDS * 64 * 8];   // 96 KB

    const int tid  = threadIdx.x;
    const int lane = tid & 63;
    const int w    = tid >> 6;      // wave 0..7, owns cols [64w, 64w+64)
    const int q    = lane >> 4;     // 0..3
    const int mr   = lane & 15;
    const int blk  = blockIdx.x;    // batch group
    const int bb   = blk * 16;

    // h0 = 0
    for (int i = tid; i < 16 * RS2; i += 512) a_lds[0][i] = 0;

    // preload LDS-resident W chunks (kc 0..2), fragment layout
    for (int i = tid; i < 32 * KC_LDS * 64; i += 512) {
        int l  = i & 63;
        int kc = (i >> 6) % KC_LDS;
        int nt = (i >> 6) / KC_LDS;
        *(short8*)&w_lds[(size_t)i * 8] =
            *(const short8*)(Bpack + ((size_t)(nt * NKC + kc) * 64 + l) * 8);
    }

    // W_hh kc 3..5, pinned register-resident (48 VGPRs)
    short8 wreg[KC_REG][4];
#pragma unroll
    for (int r = 0; r < KC_REG; ++r)
#pragma unroll
        for (int j = 0; j < 4; ++j)
            wreg[r][j] = *(const short8*)(Bpack +
                ((size_t)((4 * w + j) * NKC + KC_LDS + r) * 64 + lane) * 8);
#pragma unroll
    for (int r = 0; r < KC_REG; ++r)
#pragma unroll
        for (int j = 0; j < 4; ++j)
            asm volatile("" : "+v"(wreg[r][j]));

    __syncthreads();  // a_lds[0] zeros + w_lds visible

    f32x4 acc[4];
    short8 sb[3][4];   // streamed prefetch buffers (3 kc in flight)

    // dense xp: block's tile for step t starts at (t*16+blk)*512*16 elems
    const unsigned short* xpt = xp + ((size_t)blk * 512) * 16;
    const size_t xstride = (size_t)16 * 512 * 16;   // per-t elems

    for (int t = 0; t < T_; ++t) {
        const unsigned short* A = a_lds[t & 1];
        unsigned short* An      = a_lds[(t & 1) ^ 1];

        // streamed W issue: kc 6,7,8 into sb[0..2]
#pragma unroll
        for (int s = 0; s < 3; ++s)
#pragma unroll
            for (int j = 0; j < 4; ++j)
                sb[s][j] = *(const short8*)(Bpack +
                    ((size_t)((4 * w + j) * NKC + KC_LDS + KC_REG + s) * 64 + lane) * 8);

        // xp prefetch (dense: contiguous 512B per wave per j), consumed in epilogue
        ushort4 xpr[4];
#pragma unroll
        for (int j = 0; j < 4; ++j) {
            int col = (4 * w + j) * 16 + mr;
            xpr[j] = *(const ushort4*)(xpt + (size_t)col * 16 + q * 4);
        }

#pragma unroll
        for (int j = 0; j < 4; ++j) acc[j] = (f32x4)(0.0f);

        // --- LDS-resident kcs (0..2) ---
#pragma unroll
        for (int kc = 0; kc < KC_LDS; ++kc) {
            short8 af = *(const short8*)&A[mr * RS2 + kc * 32 + q * 8];
#pragma unroll
            for (int j = 0; j < 4; ++j) {
                short8 bfr = *(const short8*)&w_lds[
                    (size_t)(((4 * w + j) * KC_LDS + kc) * 64 + lane) * 8];
                acc[j] = __builtin_amdgcn_mfma_f32_16x16x32_bf16(af, bfr, acc[j], 0, 0, 0);
            }
        }
        // --- register-resident kcs (3..5) ---
#pragma unroll
        for (int r = 0; r < KC_REG; ++r) {
            short8 af = *(const short8*)&A[mr * RS2 + (KC_LDS + r) * 32 + q * 8];
#pragma unroll
            for (int j = 0; j < 4; ++j)
                acc[j] = __builtin_amdgcn_mfma_f32_16x16x32_bf16(af, wreg[r][j], acc[j], 0, 0, 0);
        }
        // --- streamed kcs (6..15), rolling 3-deep refill ---
#pragma unroll
        for (int s = 0; s < KC_STR; ++s) {
            int kc = KC_LDS + KC_REG + s;
            short8 af = *(const short8*)&A[mr * RS2 + kc * 32 + q * 8];
#pragma unroll
            for (int j = 0; j < 4; ++j)
                acc[j] = __builtin_amdgcn_mfma_f32_16x16x32_bf16(af, sb[s % 3][j], acc[j], 0, 0, 0);
            if (s + 3 < KC_STR) {
#pragma unroll
                for (int j = 0; j < 4; ++j)
                    sb[s % 3][j] = *(const short8*)(Bpack +
                        ((size_t)((4 * w + j) * NKC + kc + 3) * 64 + lane) * 8);
            }
        }

        // epilogue: h_{t+1} = tanh(acc + xp); D row m = q*4+e, col = (4w+j)*16+mr
#pragma unroll
        for (int j = 0; j < 4; ++j) {
            int col = (4 * w + j) * 16 + mr;
            const unsigned short* xj = (const unsigned short*)&xpr[j];
#pragma unroll
            for (int e = 0; e < 4; ++e) {
                float hv = fast_tanh(acc[j][e] + bf2f(xj[e]));
                An[(q * 4 + e) * RS2 + col] = f2bf(hv);
            }
        }
        xpt += xstride;
        __syncthreads();   // h_{t+1} visible; fences A reads vs next overwrite
    }

    // out[b] = h_T[b] . fc_w + fc_b  (32 threads per batch row); h_T in buf 0 (T even)
    {
        const int row = tid >> 5;
        const int l32 = tid & 31;
        float s = 0.0f;
        for (int k = l32; k < H_; k += 32)
            s += bf2f(a_lds[0][row * RS2 + k]) * fc_w[k];
#pragma unroll
        for (int off = 16; off > 0; off >>= 1)
            s += __shfl_down(s, off, 32);
        if (l32 == 0) out[bb + row] = s + fc_b[0];
    }
}

// ---------------------------------------------------------------------------
// FALLBACK PATH — round-0 kernel verbatim (640 KB workspace, measured 1214 µs)
// ---------------------------------------------------------------------------
#define FB_NKC   20
#define FB_NKC_H 16
#define FB_RS   648
#define FB_KC_LDS 4
#define FB_KC_REG 5
#define FB_KC_STR 7

__global__ void pack_w20(const float* __restrict__ W_ih,
                         const float* __restrict__ W_hh,
                         unsigned short* __restrict__ Bpack) {
    int idx = blockIdx.x * blockDim.x + threadIdx.x;
    if (idx >= 32 * FB_NKC * 64) return;
    int lane = idx & 63;
    int kc   = (idx >> 6) % FB_NKC;
    int nt   = (idx >> 6) / FB_NKC;
    int n  = nt * 16 + (lane & 15);
    int k0 = kc * 32 + (lane >> 4) * 8;
    unsigned short* dst = Bpack + (size_t)idx * 8;
#pragma unroll
    for (int e = 0; e < 8; ++e) {
        int k = k0 + e;
        float v = (k < H_) ? W_hh[n * H_ + k] : W_ih[n * I_ + (k - H_)];
        dst[e] = f2bf(v);
    }
}

__global__ __launch_bounds__(512, 2)
void rnn_fb(const float* __restrict__ x,
            const unsigned short* __restrict__ Bpack,
            const float* __restrict__ b_ih,
            const float* __restrict__ b_hh,
            const float* __restrict__ fc_w,
            const float* __restrict__ fc_b,
            float* __restrict__ out) {
    __shared__ __align__(16) unsigned short a_lds[16 * FB_RS];
    __shared__ __align__(16) unsigned short w_lds[32 * FB_KC_LDS * 64 * 8];

    const int tid  = threadIdx.x;
    const int lane = tid & 63;
    const int w    = tid >> 6;
    const int q    = lane >> 4;
    const int mr   = lane & 15;
    const int bb   = blockIdx.x * 16;

    for (int i = tid; i < 16 * FB_RS; i += 512) a_lds[i] = 0;

    for (int i = tid; i < 32 * FB_KC_LDS * 64; i += 512) {
        int l  = i & 63;
        int kc = (i >> 6) & (FB_KC_LDS - 1);
        int nt = i >> 8;
        *(short8*)&w_lds[(size_t)i * 8] =
            *(const short8*)(Bpack + ((size_t)(nt * FB_NKC + kc) * 64 + l) * 8);
    }

    float bias[4];
#pragma unroll
    for (int j = 0; j < 4; ++j) {
        int col = (4 * w + j) * 16 + mr;
        bias[j] = b_ih[col] + b_hh[col];
    }

    short8 wih[4][4];
#pragma unroll
    for (int j = 0; j < 4; ++j)
#pragma unroll
        for (int kx = 0; kx < 4; ++kx)
            wih[j][kx] = *(const short8*)(Bpack +
                ((size_t)((4 * w + j) * FB_NKC + FB_NKC_H + kx) * 64 + lane) * 8);

    short8 wreg[FB_KC_REG][4];
#pragma unroll
    for (int r = 0; r < FB_KC_REG; ++r)
#pragma unroll
        for (int j = 0; j < 4; ++j)
            wreg[r][j] = *(const short8*)(Bpack +
                ((size_t)((4 * w + j) * FB_NKC + FB_KC_LDS + r) * 64 + lane) * 8);

    const int xrow = tid >> 5;
    const int xc   = (tid & 31) * 4;
    const float* xbase = x + (size_t)(bb + xrow) * T_ * I_ + xc;
    float4 xreg = *(const float4*)(xbase);

    __syncthreads();

    f32x4 acc[4];
    short8 sb[3][4];

    for (int t = 0; t < T_; ++t) {
#pragma unroll
        for (int s = 0; s < 3; ++s)
#pragma unroll
            for (int j = 0; j < 4; ++j)
                sb[s][j] = *(const short8*)(Bpack +
                    ((size_t)((4 * w + j) * FB_NKC + FB_KC_LDS + FB_KC_REG + s) * 64 + lane) * 8);

        {
            ushort4 xs;
            xs.x = f2bf(xreg.x); xs.y = f2bf(xreg.y);
            xs.z = f2bf(xreg.z); xs.w = f2bf(xreg.w);
            *(ushort4*)&a_lds[xrow * FB_RS + H_ + xc] = xs;
        }
        __syncthreads();

        if (t + 1 < T_)
            xreg = *(const float4*)(xbase + (size_t)(t + 1) * I_);

#pragma unroll
        for (int j = 0; j < 4; ++j) acc[j] = (f32x4)(0.0f);

#pragma unroll
        for (int kc = 0; kc < FB_KC_LDS; ++kc) {
            short8 af = *(const short8*)&a_lds[mr * FB_RS + kc * 32 + q * 8];
#pragma unroll
            for (int j = 0; j < 4; ++j) {
                short8 bfr = *(const short8*)&w_lds[
                    (size_t)(((4 * w + j) * FB_KC_LDS + kc) * 64 + lane) * 8];
                acc[j] = __builtin_amdgcn_mfma_f32_16x16x32_bf16(af, bfr, acc[j], 0, 0, 0);
            }
        }
#pragma unroll
        for (int r = 0; r < FB_KC_REG; ++r) {
            short8 af = *(const short8*)&a_lds[mr * FB_RS + (FB_KC_LDS + r) * 32 + q * 8];
#pragma unroll
            for (int j = 0; j < 4; ++j)
                acc[j] = __builtin_amdgcn_mfma_f32_16x16x32_bf16(af, wreg[r][j], acc[j], 0, 0, 0);
        }
#pragma unroll
        for (int kx = 0; kx < 4; ++kx) {
            short8 af = *(const short8*)&a_lds[mr * FB_RS + H_ + kx * 32 + q * 8];
#pragma unroll
            for (int j = 0; j < 4; ++j)
                acc[j] = __builtin_amdgcn_mfma_f32_16x16x32_bf16(af, wih[j][kx], acc[j], 0, 0, 0);
        }
#pragma unroll
        for (int s = 0; s < FB_KC_STR; ++s) {
            int kc = FB_KC_LDS + FB_KC_REG + s;
            short8 af = *(const short8*)&a_lds[mr * FB_RS + kc * 32 + q * 8];
#pragma unroll
            for (int j = 0; j < 4; ++j)
                acc[j] = __builtin_amdgcn_mfma_f32_16x16x32_bf16(af, sb[s % 3][j], acc[j], 0, 0, 0);
            if (s + 3 < FB_KC_STR) {
#pragma unroll
                for (int j = 0; j < 4; ++j)
                    sb[s % 3][j] = *(const short8*)(Bpack +
                        ((size_t)((4 * w + j) * FB_NKC + kc + 3) * 64 + lane) * 8);
            }
        }
        __syncthreads();

#pragma unroll
        for (int j = 0; j < 4; ++j) {
            int col = (4 * w + j) * 16 + mr;
#pragma unroll
            for (int e = 0; e < 4; ++e) {
                float hv = fast_tanh(acc[j][e] + bias[j]);
                a_lds[(q * 4 + e) * FB_RS + col] = f2bf(hv);
            }
        }
    }
    __syncthreads();

    {
        const int row = tid >> 5;
        const int l32 = tid & 31;
        float s = 0.0f;
        for (int k = l32; k < H_; k += 32)
            s += bf2f(a_lds[row * FB_RS + k]) * fc_w[k];
#pragma unroll
        for (int off = 16; off > 0; off >>= 1)
            s += __shfl_down(s, off, 32);
        if (l32 == 0) out[bb + row] = s + fc_b[0];
    }
}

// ---------------------------------------------------------------------------

extern "C" void kernel_launch(void* const* d_in, const int* in_sizes, int n_in,
                              void* d_out, int out_size, void* d_ws, size_t ws_size,
                              hipStream_t stream) {
    const float* x    = (const float*)d_in[0];
    const float* W_ih = (const float*)d_in[1];
    const float* W_hh = (const float*)d_in[2];
    const float* b_ih = (const float*)d_in[3];
    const float* b_hh = (const float*)d_in[4];
    const float* fc_w = (const float*)d_in[5];
    const float* fc_b = (const float*)d_in[6];

    const size_t BP_SZ  = (size_t)32 * NKC * 64 * 8 * 2;   // 512 KB
    const size_t WIA_SZ = (size_t)32 * 4 * 64 * 8 * 2;     // 128 KB
    const size_t BV_SZ  = (size_t)H_ * 4;                  // 2 KB
    const size_t XP_OFF = BP_SZ + WIA_SZ + BV_SZ;
    const size_t NEED_FAST = XP_OFF + (size_t)T_ * H_ * B_ * 2;   // +64 MB

    if (ws_size >= NEED_FAST) {
        unsigned short* Bpack = (unsigned short*)d_ws;
        unsigned short* wia   = (unsigned short*)((char*)d_ws + BP_SZ);
        float*          bv    = (float*)((char*)d_ws + BP_SZ + WIA_SZ);
        unsigned short* xp    = (unsigned short*)((char*)d_ws + XP_OFF);
        pack_all<<<128, 256, 0, stream>>>(W_hh, W_ih, b_ih, b_hh, Bpack, wia, bv);
        xproj_k<<<dim3(T_ / 4, 16), 256, 0, stream>>>(x, wia, bv, xp);
        rnn_fast<<<16, 512, 0, stream>>>(Bpack, xp, fc_w, fc_b, (float*)d_out);
    } else {
        unsigned short* Bpack = (unsigned short*)d_ws;                 // 640 KB
        pack_w20<<<160, 256, 0, stream>>>(W_ih, W_hh, Bpack);
        rnn_fb<<<16, 512, 0, stream>>>(x, Bpack, b_ih, b_hh, fc_w, fc_b, (float*)d_out);
    }
}